// Round 7
// baseline (178.285 us; speedup 1.0000x reference)
//
#include <hip/hip_runtime.h>
#include <hip/hip_cooperative_groups.h>

namespace cg = cooperative_groups;

// CapsuleLayer dynamic routing, MI355X fp32.
// x: [B=64, N=2048, I=8], W: [J=32, N=2048, D=16, I=8], out v: [B=64, J=32, D=16]
//
// b_t = u_hat . (v_0+...+v_{t-1})  =>  u_hat (256 MB) never materialized;
// each phase recomputes it in registers from x + W (L2-resident via XCD
// swizzle). R7: cooperative fused kernel (3 phases + reduces, grid.sync
// between stages, W tile persists in registers across phases) — but GATED
// by host-side occupancy/support queries with the proven R5 six-kernel
// pipeline as fallback (R6's coop launch was silently rejected: out == 0).

#define BB_ 64
#define NN_ 2048
#define II_ 8
#define JJ_ 32
#define DD_ 16
#define NCHUNKS 128
#define CHUNK 16       /* n's per block */
#define BG 8           /* b's per block */
#define NBG (BB_ / BG) /* 8 */
#define EPS_ 1e-7f

#define PARTIAL_FLOATS (NCHUNKS * BB_ * JJ_ * DD_) /* 4M floats = 16.8 MB */
#define OUT_ELEMS (BB_ * JJ_ * DD_)                /* 32768 */

typedef __attribute__((ext_vector_type(2))) float v2f;

// DPP helpers (VALU-pipe cross-lane). CTRL must be an immediate.
template <int CTRL>
__device__ __forceinline__ float dpp_add(float v) {
  const int s = __builtin_amdgcn_update_dpp(
      0, __builtin_bit_cast(int, v), CTRL, 0xf, 0xf, true);
  return v + __builtin_bit_cast(float, s);
}
#define DPP_QP_XOR1 0xB1      /* quad_perm [1,0,3,2]  : lane ^ 1 */
#define DPP_QP_XOR2 0x4E      /* quad_perm [2,3,0,1]  : lane ^ 2 */
#define DPP_HALF_MIRROR 0x141 /* mirror within 8      : lane ^ 7 */
#define DPP_ROR8 0x128        /* row_ror:8 (16-lane)  : lane ^ 8 */

// ---- shared inner machinery (identical math in fused & split paths) ----

// One phase's accumulation for this thread. r==0: uniform coupling.
// Returns s (v2f per b). Requires lmat/cmat shared arrays.
template <int PHASE>
__device__ __forceinline__ void phase_body(
    const float* __restrict__ x, const float* wp, const float* __restrict__ V,
    float (*lmat)[JJ_], float (*cmat)[JJ_], int tid, int j, int p, int b0,
    int n0, v2f* s, float4& wc0, float4& wc1, float4& wc2, float4& wc3) {
  float v0r[BG], v1r[BG];
  if (PHASE > 0) {
#pragma unroll
    for (int b = 0; b < BG; ++b) {
      const float2 vv =
          *(const float2*)&V[((size_t)(b0 + b) * JJ_ + j) * DD_ + 2 * p];
      v0r[b] = vv.x;
      v1r[b] = vv.y;
    }
  }

#pragma unroll
  for (int b = 0; b < BG; ++b) s[b] = (v2f)(0.f);

  for (int nl = 0; nl < CHUNK; ++nl) {
    const int n = n0 + nl;
    // Register double-buffer; wrap so wc ends holding nl=0 for the next phase.
    const int nn = (nl + 1) & (CHUNK - 1);
    const float4* np_ = (const float4*)(wp + (size_t)nn * (DD_ * II_));
    const float4 wn0 = np_[0], wn1 = np_[1], wn2 = np_[2], wn3 = np_[3];

    // Pack W pairs {W[d0][i], W[d1][i]} once per nl -> v_pk_fma operands.
    v2f wk0 = {wc0.x, wc2.x}, wk1 = {wc0.y, wc2.y};
    v2f wk2 = {wc0.z, wc2.z}, wk3 = {wc0.w, wc2.w};
    v2f wk4 = {wc1.x, wc3.x}, wk5 = {wc1.y, wc3.y};
    v2f wk6 = {wc1.z, wc3.z}, wk7 = {wc1.w, wc3.w};

    v2f u[BG];
#pragma unroll
    for (int b = 0; b < BG; ++b) {
      // Wave-uniform x row (b, n uniform): scalar-load path, no LDS.
      const float4* __restrict__ xr =
          (const float4*)(x + ((size_t)(b0 + b) * NN_ + n) * II_);
      const float4 xa = xr[0];
      const float4 xb = xr[1];
      v2f acc = wk0 * xa.x;
      acc += wk1 * xa.y;
      acc += wk2 * xa.z;
      acc += wk3 * xa.w;
      acc += wk4 * xb.x;
      acc += wk5 * xb.y;
      acc += wk6 * xb.z;
      acc += wk7 * xb.w;
      u[b] = acc;
    }

    if (PHASE == 0) {
#pragma unroll
      for (int b = 0; b < BG; ++b) s[b] += u[b];
    } else {
      // logits: 2-elem partial per lane, xor butterfly over the 8 p-lanes.
#pragma unroll
      for (int b = 0; b < BG; ++b) {
        float lp = u[b].x * v0r[b] + u[b].y * v1r[b];
        lp = dpp_add<DPP_QP_XOR1>(lp);
        lp = dpp_add<DPP_QP_XOR2>(lp);
        lp = dpp_add<DPP_HALF_MIRROR>(lp);
        if (p == 0) lmat[b][j] = lp;
      }
      __syncthreads();
      // softmax over j (32) x 8 b = 256 threads, 1 entry each.
      // |logit| <= ~1.5: exp safe without max subtraction (validated R2-R5).
      {
        const int jj = tid & 31;
        const int bb = tid >> 5;
        float e0 = __expf(lmat[bb][jj]);
        float m0 = e0;
        m0 = dpp_add<DPP_QP_XOR1>(m0);
        m0 = dpp_add<DPP_QP_XOR2>(m0);
        m0 = dpp_add<DPP_HALF_MIRROR>(m0);
        m0 = dpp_add<DPP_ROR8>(m0);
        m0 += __shfl_xor(m0, 16);
        cmat[bb][jj] = e0 * __builtin_amdgcn_rcpf(m0);
      }
      __syncthreads();
#pragma unroll
      for (int b = 0; b < BG; ++b) {
        const float c = cmat[b][j];  // broadcast (all p-lanes same addr)
        s[b] += u[b] * c;            // one v_pk_fma
      }
      // no 3rd sync: next iter's lmat writes are gated by the cmat barrier.
    }

    wc0 = wn0;
    wc1 = wn1;
    wc2 = wn2;
    wc3 = wn3;
  }
}

__device__ __forceinline__ void store_partials(float* __restrict__ partial,
                                               const v2f* s, int chunk, int b0,
                                               int j, int p, float scale) {
#pragma unroll
  for (int b = 0; b < BG; ++b) {
    const size_t off =
        ((size_t)chunk * BB_ + (b0 + b)) * (JJ_ * DD_) + j * DD_ + 2 * p;
    *(float2*)&partial[off] = make_float2(s[b].x * scale, s[b].y * scale);
  }
}

// ---- fused cooperative kernel ----
__global__ __launch_bounds__(256, 4) void caps_fused(
    const float* __restrict__ x, const float* __restrict__ W,
    float* __restrict__ partial, float* __restrict__ V,
    float* __restrict__ out) {
  cg::grid_group grid = cg::this_grid();
  const int tid = threadIdx.x;
  const int j = tid >> 3;
  const int p = tid & 7;
  const int chunk = blockIdx.x & (NCHUNKS - 1);
  const int bg = blockIdx.x >> 7;
  const int b0 = bg * BG;
  const int n0 = chunk * CHUNK;

  __shared__ float lmat[BG][JJ_];
  __shared__ float cmat[BG][JJ_];

  const float* wp = W + (size_t)j * (NN_ * DD_ * II_) +
                    (size_t)n0 * (DD_ * II_) + (size_t)p * 16;
  float4 wc0 = ((const float4*)wp)[0];
  float4 wc1 = ((const float4*)wp)[1];
  float4 wc2 = ((const float4*)wp)[2];
  float4 wc3 = ((const float4*)wp)[3];

  v2f s[BG];
  for (int r = 0; r < 3; ++r) {
    if (r == 0)
      phase_body<0>(x, wp, V, lmat, cmat, tid, j, p, b0, n0, s, wc0, wc1, wc2, wc3);
    else
      phase_body<1>(x, wp, V, lmat, cmat, tid, j, p, b0, n0, s, wc0, wc1, wc2, wc3);

    store_partials(partial, s, chunk, b0, j, p, (r == 0) ? (1.0f / 32.0f) : 1.0f);

    grid.sync();  // partials visible grid-wide

    // Reduce + squash on blocks 0..127 (one thread per output element).
    if (blockIdx.x < OUT_ELEMS / 256) {
      const int t = blockIdx.x * 256 + tid;
      float sum = 0.f;
#pragma unroll 8
      for (int c = 0; c < NCHUNKS; ++c)
        sum += partial[(size_t)c * OUT_ELEMS + t];
      float ss = sum * sum;  // squash denom over d (16 consecutive lanes)
      ss += __shfl_xor(ss, 1);
      ss += __shfl_xor(ss, 2);
      ss += __shfl_xor(ss, 4);
      ss += __shfl_xor(ss, 8);
      const float v = sum / sqrtf(ss + EPS_);
      if (r == 0)
        V[t] = v;
      else if (r == 1)
        V[t] += v;
      else
        out[t] = v;
    }

    if (r < 2) grid.sync();  // V visible before next phase reads it
  }
}

// ---- split-path kernels (R5, proven @177.9us) ----
template <int PHASE>
__global__ __launch_bounds__(256, 4) void caps_phase(
    const float* __restrict__ x, const float* __restrict__ W,
    const float* __restrict__ V, float* __restrict__ partial) {
  const int tid = threadIdx.x;
  const int j = tid >> 3;
  const int p = tid & 7;
  const int chunk = blockIdx.x & (NCHUNKS - 1);
  const int bg = blockIdx.x >> 7;
  const int b0 = bg * BG;
  const int n0 = chunk * CHUNK;

  __shared__ float lmat[BG][JJ_];
  __shared__ float cmat[BG][JJ_];

  const float* wp = W + (size_t)j * (NN_ * DD_ * II_) +
                    (size_t)n0 * (DD_ * II_) + (size_t)p * 16;
  float4 wc0 = ((const float4*)wp)[0];
  float4 wc1 = ((const float4*)wp)[1];
  float4 wc2 = ((const float4*)wp)[2];
  float4 wc3 = ((const float4*)wp)[3];

  v2f s[BG];
  phase_body<PHASE>(x, wp, V, lmat, cmat, tid, j, p, b0, n0, s, wc0, wc1, wc2,
                    wc3);
  store_partials(partial, s, chunk, b0, j, p,
                 (PHASE == 0) ? (1.0f / 32.0f) : 1.0f);
}

template <int MODE>
__global__ __launch_bounds__(128) void caps_reduce(
    const float* __restrict__ partial, float* __restrict__ V,
    float* __restrict__ out) {
  const int t = blockIdx.x * 128 + threadIdx.x;  // [0, B*J*D)
  float s = 0.f;
#pragma unroll 8
  for (int c = 0; c < NCHUNKS; ++c)
    s += partial[(size_t)c * OUT_ELEMS + t];
  float ss = s * s;
  ss += __shfl_xor(ss, 1);
  ss += __shfl_xor(ss, 2);
  ss += __shfl_xor(ss, 4);
  ss += __shfl_xor(ss, 8);
  const float v = s / sqrtf(ss + EPS_);
  if (MODE == 0)
    V[t] = v;
  else if (MODE == 1)
    V[t] += v;
  else
    out[t] = v;
}

extern "C" void kernel_launch(void* const* d_in, const int* in_sizes, int n_in,
                              void* d_out, int out_size, void* d_ws,
                              size_t ws_size, hipStream_t stream) {
  const float* x = (const float*)d_in[0];
  const float* W = (const float*)d_in[1];
  float* out = (float*)d_out;
  float* partial = (float*)d_ws;        // 16.8 MB
  float* V = partial + PARTIAL_FLOATS;  // 128 KB

  // Capture-safe host-side gating (no stream ops): coop support + occupancy.
  int dev = 0;
  (void)hipGetDevice(&dev);
  int coop_attr = 0;
  (void)hipDeviceGetAttribute(&coop_attr, hipDeviceAttributeCooperativeLaunch,
                              dev);
  int nb = 0;
  (void)hipOccupancyMaxActiveBlocksPerMultiprocessor(&nb, caps_fused, 256, 0);

  hipError_t e = hipErrorUnknown;
  if (coop_attr && nb >= 4) {
    void* args[] = {(void*)&x, (void*)&W, (void*)&partial, (void*)&V,
                    (void*)&out};
    e = hipLaunchCooperativeKernel((void*)caps_fused, dim3(NBG * NCHUNKS),
                                   dim3(256), args, 0, stream);
  }
  if (e != hipSuccess) {
    (void)hipGetLastError();  // clear sticky error, fall back to split path
    const dim3 kgrid(NBG * NCHUNKS);            // 1024 blocks x 256 threads
    const dim3 rgrid(OUT_ELEMS / 128);          // 256 blocks x 128 threads
    caps_phase<0><<<kgrid, 256, 0, stream>>>(x, W, nullptr, partial);
    caps_reduce<0><<<rgrid, 128, 0, stream>>>(partial, V, out);
    caps_phase<1><<<kgrid, 256, 0, stream>>>(x, W, V, partial);
    caps_reduce<1><<<rgrid, 128, 0, stream>>>(partial, V, out);
    caps_phase<2><<<kgrid, 256, 0, stream>>>(x, W, V, partial);
    caps_reduce<2><<<rgrid, 128, 0, stream>>>(partial, V, out);
  }
}